// Round 6
// baseline (212.492 us; speedup 1.0000x reference)
//
#include <hip/hip_runtime.h>
#include <hip/hip_bf16.h>
#include <stdint.h>

// Problem constants (B=8, S=2048, E=1024, H=128, DK=8)
#define M_DIM 16384   // B*S
#define N_DIM 1024    // E (output features)
#define K_DIM 1024    // E (reduction)

typedef __attribute__((ext_vector_type(8))) short short8;
typedef __attribute__((ext_vector_type(4))) float f32x4;

// async global->LDS, 16B per lane. LDS dest must be wave-uniform base + lane*16.
#define GLD_LDS(g, l) __builtin_amdgcn_global_load_lds( \
    (const __attribute__((address_space(1))) unsigned int*)(g), \
    (__attribute__((address_space(3))) unsigned int*)(l), 16, 0, 0)

__device__ __forceinline__ unsigned short f2bf(float f) {
  union { float f; unsigned int u; } v;
  v.f = f;
  unsigned int u = v.u + 0x7FFFu + ((v.u >> 16) & 1u);  // RNE
  return (unsigned short)(u >> 16);
}

// W -> bf16 cast only (6 MB traffic, ~2 us). A-prep is FUSED into the GEMM.
#define PREP_W_BLOCKS (N_DIM * K_DIM / (256 * 8))   // 512
__global__ __launch_bounds__(256) void prep_w(const float* __restrict__ W,
                                              unsigned short* __restrict__ Wb) {
  const long i = ((long)blockIdx.x * 256 + threadIdx.x) * 8;
  float4 w0 = *(const float4*)(W + i);
  float4 w1 = *(const float4*)(W + i + 4);
  union { unsigned short s[8]; short8 v; } o;
  o.s[0] = f2bf(w0.x); o.s[1] = f2bf(w0.y); o.s[2] = f2bf(w0.z); o.s[3] = f2bf(w0.w);
  o.s[4] = f2bf(w1.x); o.s[5] = f2bf(w1.y); o.s[6] = f2bf(w1.z); o.s[7] = f2bf(w1.w);
  *(short8*)(Wb + i) = o.v;
}

// C[m,n] = sum_k cos(x[m,k]+theta[k]) * Wb[n,k] + bias[n].  x:[M,K] f32,
// Wb:[N,K] bf16, C:[M,N] f32.
//
// R7: FUSED prep-A + GEMM. r2/r4/r6 all plateaued at ~50 us / 25% MfmaUtil
// regardless of sync schedule -> schedule wasn't the constraint. MFMA busy
// (~12 us) already ~= the 13.7 us floor; the rest was prep round-trip,
// 1-block/CU lockstep (no inter-block overlap), and the epilogue write burst.
// This version: A = bf16(cos(x+theta)) computed in-kernel (reg-stage x f32 ->
// VALU -> ds_write), removing the 170 MB prep pass entirely. 128x128 tile,
// 4 waves, BK=64, LDS 64 KB -> 2 blocks/CU: desynced blocks overlap each
// other's barrier/epilogue stalls.
//
// Schedule (1 __syncthreads per K-tile; buffers [parity p][kh]):
//   iter t: VMW(0)                       // x(t) regs + B(t) LDS landed
//           WRITEA -> bufA[p]            // cos+pack, 4 ds_write_b128
//           __syncthreads()              // nothing vmem outstanding -> free drain
//           if t<15: STAGEB(t+1)->bufB[p^1] (global_load_lds, safe: all waves
//                    past sync => compute(t-1) readers of bufB[p^1] done);
//                    LOADA(t+1) -> regs  (latency hidden under compute(t))
//           COMPUTE(p)                   // 16 ds_read_b128 + 32 MFMA
// Race ledger: bufA[p] written between sync(t-1) and sync(t), last read
// compute(t-2) (pre-sync(t-1)) -> safe. bufB[p^1] written post-sync(t), last
// read compute(t-1) (pre-sync(t)) -> safe. Reg WAR (WRITEA then LOADA) is
// program-order safe.
//
// LDS unit = 8 KB = 128 rows x 32 k bf16. chunk(row,kc) at elem
// (row>>3)*256 + kc*64 + (row&7)*8  == linear in (i2*256+tid)*8 for the
// writer (re-verified algebraically) and conflict-free for ds_read_b128
// (8 consecutive frag rows at fixed kc = 8 distinct 16B slots / 128B).
//
// Grid 1024 blocks (4 rounds of 2/CU -> natural stagger). XCD banding:
// xcd=L&7 owns M-tiles [16c,16c+16); the 8 N-blocks sharing an A-panel are
// dispatch-adjacent on one XCD -> x panel read ~once from HBM, x8 via L2.
__global__ __launch_bounds__(256, 2) void gemm_fused(const float* __restrict__ x,
                                                     const float* __restrict__ theta,
                                                     const unsigned short* __restrict__ Bt,
                                                     const float* __restrict__ bias,
                                                     float* __restrict__ C) {
  constexpr int NTT = K_DIM / 64;  // 16 K-tiles
  __shared__ unsigned short As[4 * 4096];  // 32 KB: units [p][kh]
  __shared__ unsigned short Bs[4 * 4096];  // 32 KB
  const int tid = threadIdx.x;

  const int L = blockIdx.x;             // 0..1023
  const int xcd = L & 7;
  const int idx = L >> 3;               // 0..127
  const int by = xcd * 16 + (idx >> 3); // M-tile 0..127, banded per XCD
  const int bx = idx & 7;               // N-tile 0..7
  const int m0 = by * 128;
  const int n0 = bx * 128;

  const int lane = tid & 63;
  const int wave = tid >> 6;        // 0..3
  const int wm = (wave >> 1) * 64;  // wave origin in M (0,64)
  const int wn = (wave & 1) * 64;   // wave origin in N (0,64)
  const int fr = lane & 15;
  const int fq = lane >> 4;

  f32x4 acc[4][4] = {};

  // Staging geometry: thread tid owns chunk column kc, rows {srow, srow+64}.
  const int srow = ((tid >> 5) << 3) | (tid & 7);  // 0..63
  const int kc = (tid >> 3) & 3;
  const float* xg = x + (long)(m0 + srow) * K_DIM + kc * 8;
  const unsigned short* Bg = Bt + (long)(n0 + srow) * K_DIM + kc * 8;
  unsigned short* BsD = Bs + tid * 8;

  float4 xa[4][2];  // [kh*2+i2][half] staged x
  float4 th[2][2];  // [kh][half] staged theta

#define LOADA(T) do { \
    _Pragma("unroll") \
    for (int kh = 0; kh < 2; ++kh) { \
      th[kh][0] = *(const float4*)(theta + (T) * 64 + kh * 32 + kc * 8); \
      th[kh][1] = *(const float4*)(theta + (T) * 64 + kh * 32 + kc * 8 + 4); \
      _Pragma("unroll") \
      for (int i2 = 0; i2 < 2; ++i2) { \
        const float* g_ = xg + (long)i2 * 64 * K_DIM + (T) * 64 + kh * 32; \
        xa[kh * 2 + i2][0] = *(const float4*)(g_); \
        xa[kh * 2 + i2][1] = *(const float4*)(g_ + 4); \
      } \
    } \
  } while (0)

#define STAGEB(P, T) do { \
    _Pragma("unroll") \
    for (int kh = 0; kh < 2; ++kh) \
      _Pragma("unroll") \
      for (int i2 = 0; i2 < 2; ++i2) \
        GLD_LDS(Bg + (long)i2 * 64 * K_DIM + (T) * 64 + kh * 32, \
                BsD + ((P) * 2 + kh) * 4096 + i2 * 2048); \
  } while (0)

#define WRITEA(P) do { \
    _Pragma("unroll") \
    for (int kh = 0; kh < 2; ++kh) \
      _Pragma("unroll") \
      for (int i2 = 0; i2 < 2; ++i2) { \
        union { unsigned short s[8]; short8 v; } o; \
        o.s[0] = f2bf(__cosf(xa[kh * 2 + i2][0].x + th[kh][0].x)); \
        o.s[1] = f2bf(__cosf(xa[kh * 2 + i2][0].y + th[kh][0].y)); \
        o.s[2] = f2bf(__cosf(xa[kh * 2 + i2][0].z + th[kh][0].z)); \
        o.s[3] = f2bf(__cosf(xa[kh * 2 + i2][0].w + th[kh][0].w)); \
        o.s[4] = f2bf(__cosf(xa[kh * 2 + i2][1].x + th[kh][1].x)); \
        o.s[5] = f2bf(__cosf(xa[kh * 2 + i2][1].y + th[kh][1].y)); \
        o.s[6] = f2bf(__cosf(xa[kh * 2 + i2][1].z + th[kh][1].z)); \
        o.s[7] = f2bf(__cosf(xa[kh * 2 + i2][1].w + th[kh][1].w)); \
        *(short8*)(As + ((P) * 2 + kh) * 4096 + i2 * 2048 + tid * 8) = o.v; \
      } \
  } while (0)

  // Fragment read bases: elem(row,kc=fq) = (row>>3)*256 + fq*64 + (row&7)*8.
  const int baseA = ((wm >> 3) + (fr >> 3)) * 256 + fq * 64 + (fr & 7) * 8;
  const int baseB = ((wn >> 3) + (fr >> 3)) * 256 + fq * 64 + (fr & 7) * 8;

#define COMPUTE(P) do { \
    _Pragma("unroll") \
    for (int kh = 0; kh < 2; ++kh) { \
      const unsigned short* Au = As + ((P) * 2 + kh) * 4096; \
      const unsigned short* Bu = Bs + ((P) * 2 + kh) * 4096; \
      short8 af[4], bfv[4]; \
      _Pragma("unroll") \
      for (int j = 0; j < 4; ++j) bfv[j] = *(const short8*)(Bu + baseB + j * 512); \
      _Pragma("unroll") \
      for (int i = 0; i < 4; ++i) af[i] = *(const short8*)(Au + baseA + i * 512); \
      _Pragma("unroll") \
      for (int i = 0; i < 4; ++i) \
        _Pragma("unroll") \
        for (int j = 0; j < 4; ++j) \
          acc[i][j] = __builtin_amdgcn_mfma_f32_16x16x32_bf16(af[i], bfv[j], acc[i][j], 0, 0, 0); \
    } \
  } while (0)

#define VMW0() asm volatile("s_waitcnt vmcnt(0)" ::: "memory")

  // Prologue: tile 0 into parity-0 buffers / regs.
  LOADA(0);
  STAGEB(0, 0);

  for (int t = 0; t < NTT; ++t) {
    const int p = t & 1;
    VMW0();             // x(t) regs + B(t) LDS landed (issued one compute ago)
    WRITEA(p);
    __syncthreads();
    if (t < NTT - 1) {
      STAGEB(p ^ 1, t + 1);
      LOADA(t + 1);
    }
    COMPUTE(p);
  }

  // Epilogue: D[row=(lane>>4)*4+r][col=lane&15] per 16x16 frag (m89-verified).
  const int cn = lane & 15;
  const int rq = (lane >> 4) * 4;
#pragma unroll
  for (int j = 0; j < 4; ++j) {
    const int n = n0 + wn + j * 16 + cn;
    const float bv = bias[n];
#pragma unroll
    for (int i = 0; i < 4; ++i) {
      const long mb = (long)(m0 + wm + i * 16 + rq) * N_DIM + n;
#pragma unroll
      for (int r = 0; r < 4; ++r)
        C[mb + (long)r * N_DIM] = acc[i][j][r] + bv;
    }
  }
}

extern "C" void kernel_launch(void* const* d_in, const int* in_sizes, int n_in,
                              void* d_out, int out_size, void* d_ws, size_t ws_size,
                              hipStream_t stream) {
  const float* x = (const float*)d_in[0];      // [8,2048,1024]
  const float* theta = (const float*)d_in[1];  // [128,8] -> flat 1024
  const float* W = (const float*)d_in[2];      // [1024,1024]
  const float* b = (const float*)d_in[3];      // [1024]
  float* out = (float*)d_out;                  // [8,2048,1024] f32

  unsigned short* Wbf = (unsigned short*)d_ws;  // 2 MB

  hipLaunchKernelGGL(prep_w, dim3(PREP_W_BLOCKS), dim3(256), 0, stream, W, Wbf);
  hipLaunchKernelGGL(gemm_fused, dim3(M_DIM / 128 * (N_DIM / 128)), dim3(256), 0,
                     stream, x, theta, Wbf, b, out);
}

// Round 7
// 208.341 us; speedup vs baseline: 1.0199x; 1.0199x over previous
//
#include <hip/hip_runtime.h>
#include <hip/hip_bf16.h>
#include <stdint.h>

// Problem constants (B=8, S=2048, E=1024, H=128, DK=8)
#define M_DIM 16384   // B*S
#define N_DIM 1024    // E (output features)
#define K_DIM 1024    // E (reduction)

typedef __attribute__((ext_vector_type(8))) short short8;
typedef __attribute__((ext_vector_type(4))) float f32x4;

// async global->LDS, 16B per lane. LDS dest must be wave-uniform base + lane*16.
#define GLD_LDS(g, l) __builtin_amdgcn_global_load_lds( \
    (const __attribute__((address_space(1))) unsigned int*)(g), \
    (__attribute__((address_space(3))) unsigned int*)(l), 16, 0, 0)

__device__ __forceinline__ unsigned short f2bf(float f) {
  union { float f; unsigned int u; } v;
  v.f = f;
  unsigned int u = v.u + 0x7FFFu + ((v.u >> 16) & 1u);  // RNE
  return (unsigned short)(u >> 16);
}

// W -> bf16 cast only (6 MB traffic, ~2 us). A-prep is fused into the GEMM.
#define PREP_W_BLOCKS (N_DIM * K_DIM / (256 * 8))   // 512
__global__ __launch_bounds__(256) void prep_w(const float* __restrict__ W,
                                              unsigned short* __restrict__ Wb) {
  const long i = ((long)blockIdx.x * 256 + threadIdx.x) * 8;
  float4 w0 = *(const float4*)(W + i);
  float4 w1 = *(const float4*)(W + i + 4);
  union { unsigned short s[8]; short8 v; } o;
  o.s[0] = f2bf(w0.x); o.s[1] = f2bf(w0.y); o.s[2] = f2bf(w0.z); o.s[3] = f2bf(w0.w);
  o.s[4] = f2bf(w1.x); o.s[5] = f2bf(w1.y); o.s[6] = f2bf(w1.z); o.s[7] = f2bf(w1.w);
  *(short8*)(Wb + i) = o.v;
}

// C[m,n] = sum_k cos(x[m,k]+theta[k]) * Wb[n,k] + bias[n].
//
// R8 fused v2. r7 failed because the compiler SANK the x prefetch loads to
// their use site (VGPR_Count=88 vs ~176 live -> it resequenced instead of
// spilling; legal since no fence separated issue from the next vmcnt wait),
// exposing full load latency every K-tile (125 us, MfmaUtil 11%).
// Fixes here:
//  1. A-fragments built IN REGISTERS: each thread loads exactly its MFMA
//     A-frag x values. Wave layout 4M x 1N (wave tile 32x128) -> A rows are
//     unique per wave (no redundant cos), and an (i,kh,half) float4 load is
//     fully coalesced: lanes (fq*16+fr) cover 16 rows x 64B contiguous.
//     No A-LDS at all; LDS = B only (32 KB) -> 2-3 blocks/CU.
//  2. Register budget legal: acc 64 + xa 32 + th 16 + af 16 + addr ~= 170
//     under the 256-VGPR cap of __launch_bounds__(256,2) -> no spill needed.
//  3. sched_barrier(0) after the prefetch group pins loads above COMPUTE;
//     VMW(0) ("memory") at iter top stops sinking past the wait.
// Schedule per iter t (p = t&1):
//   VMW(0)            // xa(t) regs + Bs[p] landed (issued during t-1)
//   CONVA             // af = bf16(cos(xa+th)); frees xa
//   __syncthreads()   // Bs[p] visible to all waves; Bs[p^1] readers done
//   issue xa(t+1), th(t+1), STAGEB(p^1, t+1); sched_barrier(0)
//   COMPUTE(p)        // 16 ds_read_b128 (B frags) + 32 MFMA vs reg-af
// Race ledger: Bs[p^1] overwritten post-sync(t); last read COMPUTE(t-1)
// pre-sync(t) -> safe. xa WAR (CONVA then reload) is program-order safe.
//
// B LDS unit = 8 KB (128 rows x 32 k bf16), r7-verified layout:
// chunk(row,kc) at elem (row>>3)*256 + kc*64 + (row&7)*8; linear for
// global_load_lds, conflict-free for ds_read_b128.
//
// Grid 1024 (2-3 blocks/CU, 2 rounds): cross-block overlap fills barrier /
// epilogue-drain stalls. XCD banding: xcd=L&7 owns M-tiles [16c,16c+16);
// the 8 N-blocks sharing an x panel are L-stride-8 = same XCD, concurrent
// -> x read ~once from HBM, x8 via L2 (r7-PROVEN: FETCH 49 < 67 MB).
__global__ __launch_bounds__(256, 2) void gemm_fused(const float* __restrict__ x,
                                                     const float* __restrict__ theta,
                                                     const unsigned short* __restrict__ Bt,
                                                     const float* __restrict__ bias,
                                                     float* __restrict__ C) {
  constexpr int NTT = K_DIM / 64;  // 16 K-tiles
  __shared__ unsigned short Bs[4 * 4096];  // 32 KB: units [p][kh]
  const int tid = threadIdx.x;

  const int L = blockIdx.x;             // 0..1023
  const int xcd = L & 7;
  const int idx = L >> 3;               // 0..127
  const int by = xcd * 16 + (idx >> 3); // M-tile 0..127, banded per XCD
  const int bx = idx & 7;               // N-tile 0..7
  const int m0 = by * 128;
  const int n0 = bx * 128;

  const int lane = tid & 63;
  const int wave = tid >> 6;        // 0..3
  const int wm = wave * 32;         // wave tile 32(M) x 128(N)
  const int fr = lane & 15;
  const int fq = lane >> 4;

  f32x4 acc[2][8] = {};

  // ---- B staging (r7-verified machinery, 128-row tile) ----
  const int srow = ((tid >> 5) << 3) | (tid & 7);  // 0..63
  const int kc = (tid >> 3) & 3;
  const unsigned short* Bg = Bt + (long)(n0 + srow) * K_DIM + kc * 8;
  unsigned short* BsD = Bs + tid * 8;

#define STAGEB(P, T) do { \
    _Pragma("unroll") \
    for (int kh = 0; kh < 2; ++kh) \
      _Pragma("unroll") \
      for (int i2 = 0; i2 < 2; ++i2) \
        GLD_LDS(Bg + (long)i2 * 64 * K_DIM + (T) * 64 + kh * 32, \
                BsD + ((P) * 2 + kh) * 4096 + i2 * 2048); \
  } while (0)

  // ---- x direct load: thread's own A-frag elements ----
  // row(i) = m0 + wm + i*16 + fr ; cols = t*64 + kh*32 + fq*8 + (0..7)
  const float* xg0 = x + (long)(m0 + wm + fr) * K_DIM + fq * 8;

  float4 xa[2][2][2];  // [i][kh][half]
  float4 th[2][2];     // [kh][half]
  short8 af[2][2];     // [i][kh] packed bf16 A-frags

#define LOADX(T) do { \
    _Pragma("unroll") \
    for (int i = 0; i < 2; ++i) \
      _Pragma("unroll") \
      for (int kh = 0; kh < 2; ++kh) { \
        const float* g_ = xg0 + (long)i * 16 * K_DIM + (T) * 64 + kh * 32; \
        xa[i][kh][0] = *(const float4*)(g_); \
        xa[i][kh][1] = *(const float4*)(g_ + 4); \
      } \
    _Pragma("unroll") \
    for (int kh = 0; kh < 2; ++kh) { \
      th[kh][0] = *(const float4*)(theta + (T) * 64 + kh * 32 + fq * 8); \
      th[kh][1] = *(const float4*)(theta + (T) * 64 + kh * 32 + fq * 8 + 4); \
    } \
  } while (0)

#define CONVA() do { \
    _Pragma("unroll") \
    for (int i = 0; i < 2; ++i) \
      _Pragma("unroll") \
      for (int kh = 0; kh < 2; ++kh) { \
        union { unsigned short s[8]; short8 v; } o; \
        o.s[0] = f2bf(__cosf(xa[i][kh][0].x + th[kh][0].x)); \
        o.s[1] = f2bf(__cosf(xa[i][kh][0].y + th[kh][0].y)); \
        o.s[2] = f2bf(__cosf(xa[i][kh][0].z + th[kh][0].z)); \
        o.s[3] = f2bf(__cosf(xa[i][kh][0].w + th[kh][0].w)); \
        o.s[4] = f2bf(__cosf(xa[i][kh][1].x + th[kh][1].x)); \
        o.s[5] = f2bf(__cosf(xa[i][kh][1].y + th[kh][1].y)); \
        o.s[6] = f2bf(__cosf(xa[i][kh][1].z + th[kh][1].z)); \
        o.s[7] = f2bf(__cosf(xa[i][kh][1].w + th[kh][1].w)); \
        af[i][kh] = o.v; \
      } \
  } while (0)

  // B fragment read base: elem(row=j*16+fr, kc=fq) = j*512 + baseB.
  const int baseB = (fr >> 3) * 256 + fq * 64 + (fr & 7) * 8;

#define COMPUTE(P) do { \
    _Pragma("unroll") \
    for (int kh = 0; kh < 2; ++kh) { \
      const unsigned short* Bu = Bs + ((P) * 2 + kh) * 4096; \
      _Pragma("unroll") \
      for (int j = 0; j < 8; ++j) { \
        short8 bf = *(const short8*)(Bu + baseB + j * 512); \
        acc[0][j] = __builtin_amdgcn_mfma_f32_16x16x32_bf16(af[0][kh], bf, acc[0][j], 0, 0, 0); \
        acc[1][j] = __builtin_amdgcn_mfma_f32_16x16x32_bf16(af[1][kh], bf, acc[1][j], 0, 0, 0); \
      } \
    } \
  } while (0)

#define VMW0() asm volatile("s_waitcnt vmcnt(0)" ::: "memory")

  // Prologue: tile 0.
  LOADX(0);
  STAGEB(0, 0);

  for (int t = 0; t < NTT; ++t) {
    const int p = t & 1;
    VMW0();             // xa(t) + Bs[p] landed
    CONVA();            // af(t); xa now dead
    __syncthreads();    // Bs[p] visible; Bs[p^1] readers (t-1) done
    if (t < NTT - 1) {
      LOADX(t + 1);
      STAGEB(p ^ 1, t + 1);
      __builtin_amdgcn_sched_barrier(0);  // pin prefetch ABOVE compute
    }
    COMPUTE(p);
  }

  // Epilogue: D[row=(lane>>4)*4+r][col=lane&15] per 16x16 frag (m89-verified).
  const int cn = lane & 15;
  const int rq = fq * 4;
#pragma unroll
  for (int j = 0; j < 8; ++j) {
    const int n = n0 + j * 16 + cn;
    const float bv = bias[n];
#pragma unroll
    for (int i = 0; i < 2; ++i) {
      const long mb = (long)(m0 + wm + i * 16 + rq) * N_DIM + n;
#pragma unroll
      for (int r = 0; r < 4; ++r)
        C[mb + (long)r * N_DIM] = acc[i][j][r] + bv;
    }
  }
}

extern "C" void kernel_launch(void* const* d_in, const int* in_sizes, int n_in,
                              void* d_out, int out_size, void* d_ws, size_t ws_size,
                              hipStream_t stream) {
  const float* x = (const float*)d_in[0];      // [8,2048,1024]
  const float* theta = (const float*)d_in[1];  // [128,8] -> flat 1024
  const float* W = (const float*)d_in[2];      // [1024,1024]
  const float* b = (const float*)d_in[3];      // [1024]
  float* out = (float*)d_out;                  // [8,2048,1024] f32

  unsigned short* Wbf = (unsigned short*)d_ws;  // 2 MB

  hipLaunchKernelGGL(prep_w, dim3(PREP_W_BLOCKS), dim3(256), 0, stream, W, Wbf);
  hipLaunchKernelGGL(gemm_fused, dim3(M_DIM / 128 * (N_DIM / 128)), dim3(256), 0,
                     stream, x, theta, Wbf, b, out);
}